// Round 1
// baseline (412.932 us; speedup 1.0000x reference)
//
#include <hip/hip_runtime.h>

#define N_ROUTES 512
#define N_TIMES  4096
#define N_MOVES  16384
#define N_NODES  2048
#define N_CDF    8192
#define ALPHA    0.15f
#define NODE_CAP 32    // Binomial(16384,1/2048): mean 8 -> P(>32) negligible

typedef unsigned short ushort_t;
typedef __attribute__((ext_vector_type(8))) short short8;
typedef __attribute__((ext_vector_type(4))) float floatx4;

// ---------------- workspace layout (bytes) ----------------
// Abig  : bf16 [18432*512]   off 0           18,874,368   (rows 0..16383 = A, 16384..18431 = SA)
// xTbf  : bf16 [4096*512]    off 18,874,368   4,194,304
// ncnt  : int  [2048]        off 23,068,672       8,192
// nlist : int  [2048*32]     off 23,076,864     262,144
// w     : f32  [2048]        off 23,339,008       8,192
// basep : f32  [1]           off 23,347,200         256
// total ~23.4 MB

__device__ inline ushort_t f2bf(float f) {
    union { float f; unsigned u; } v; v.f = f;
    unsigned r = (v.u + 0x7FFFu + ((v.u >> 16) & 1u)) >> 16;
    return (ushort_t)r;
}

// xT[t][k] = bf16(relu(x_raw[k][t])) — LDS tile transpose, both sides coalesced.
// Fused: also writes x_out = relu(x_raw) fp32 (output 0), saving a separate kernel.
__global__ __launch_bounds__(256) void transpose_bf(const float* __restrict__ xr,
                                                    float* __restrict__ xo,
                                                    ushort_t* __restrict__ xT) {
    __shared__ float ld[64][65];
    int t0 = blockIdx.x * 64;
    int k0 = blockIdx.y * 64;
    int tid = threadIdx.x;
    int col = tid & 63;
    #pragma unroll
    for (int i = 0; i < 16; ++i) {
        int row = i * 4 + (tid >> 6);
        float v = fmaxf(xr[(size_t)(k0 + row) * N_TIMES + t0 + col], 0.f);
        ld[row][col] = v;
        xo[(size_t)(k0 + row) * N_TIMES + t0 + col] = v;   // coalesced relu write
    }
    __syncthreads();
    int trow = tid >> 2;
    int kgrp = (tid & 3) * 16;
    ushort_t __align__(16) tmp[16];
    #pragma unroll
    for (int j = 0; j < 16; ++j) tmp[j] = f2bf(ld[kgrp + j][trow]);
    ushort_t* dst = xT + (size_t)(t0 + trow) * 512 + k0 + kgrp;
    *(uint4*)dst       = ((uint4*)tmp)[0];
    *(uint4*)(dst + 8) = ((uint4*)tmp)[1];
}

// A fp32 -> bf16 (0/1 values: exact)
__global__ __launch_bounds__(256) void convA(const float* __restrict__ A,
                                             ushort_t* __restrict__ Ab) {
    size_t i = (size_t)(blockIdx.x * 256 + threadIdx.x) * 8;
    const float4* s = (const float4*)(A + i);
    float4 a = s[0], b = s[1];
    ushort_t __align__(16) t[8] = {f2bf(a.x), f2bf(a.y), f2bf(a.z), f2bf(a.w),
                                   f2bf(b.x), f2bf(b.y), f2bf(b.z), f2bf(b.w)};
    *(uint4*)(Ab + i) = *(uint4*)t;
}

__global__ __launch_bounds__(256) void build_nodes(const int* __restrict__ mnode,
                                                   int* __restrict__ ncnt,
                                                   int* __restrict__ nlist) {
    int m = blockIdx.x * blockDim.x + threadIdx.x;
    if (m >= N_MOVES) return;
    int n = mnode[m];
    int slot = atomicAdd(&ncnt[n], 1);
    if (slot < NODE_CAP) nlist[(size_t)n * NODE_CAP + slot] = m;
}

// SA[n][k] = sum over movements of node n of A[m][k] (small ints, exact in bf16)
__global__ __launch_bounds__(128) void sa_kernel(const float* __restrict__ A,
                                                 const int* __restrict__ ncnt,
                                                 const int* __restrict__ nlist,
                                                 ushort_t* __restrict__ SAb) {
    int n = blockIdx.x, tid = threadIdx.x;
    int cnt = min(ncnt[n], NODE_CAP);
    float acc0 = 0.f, acc1 = 0.f, acc2 = 0.f, acc3 = 0.f;
    for (int j = 0; j < cnt; ++j) {
        int m = nlist[(size_t)n * NODE_CAP + j];
        float4 v = *(const float4*)(A + (size_t)m * 512 + tid * 4);
        acc0 += v.x; acc1 += v.y; acc2 += v.z; acc3 += v.w;
    }
    ushort_t __align__(8) t[4] = {f2bf(acc0), f2bf(acc1), f2bf(acc2), f2bf(acc3)};
    *(uint2*)(SAb + (size_t)n * 512 + tid * 4) = *(uint2*)t;
}

// w[n] = sum_c alpha*t_free*radio/cap^4 ; base = sum_c t_free*radio
__global__ __launch_bounds__(256) void wsum_kernel(const float* __restrict__ t_free,
                                                   const float* __restrict__ cap,
                                                   const float* __restrict__ radio,
                                                   const int* __restrict__ cdf_node,
                                                   float* __restrict__ w,
                                                   float* __restrict__ basep) {
    int c = blockIdx.x * 256 + threadIdx.x;
    float tr = t_free[c] * radio[c];
    float ic = 1.0f / cap[c];
    float ic2 = ic * ic;
    atomicAdd(&w[cdf_node[c]], ALPHA * tr * ic2 * ic2);
    float b = tr;
    #pragma unroll
    for (int d = 32; d >= 1; d >>= 1) b += __shfl_down(b, d);
    if ((threadIdx.x & 63) == 0) atomicAdd(basep, b);
}

__global__ __launch_bounds__(256) void y_init(const float* __restrict__ basep,
                                              float* __restrict__ y) {
    y[blockIdx.x * 256 + threadIdx.x] = *basep;
}

#define GLOAD_LDS16(g, l) __builtin_amdgcn_global_load_lds( \
    (const __attribute__((address_space(1))) void*)(g),     \
    (__attribute__((address_space(3))) void*)(l), 16, 0, 0)

// Fused GEMM: C[18432 x 4096] = Abig @ xT^T, bf16 MFMA 16x16x32.
// Rows < 16384 -> c_pred (written).  Rows >= 16384 are nodes -> y += w[n]*f^4
// reduced in-register, never materialized.
// Tile 128x128, BK=64, 256 thr (4 waves, 64x64 quadrant each).
// v2: DOUBLE-BUFFERED LDS pipeline (T3 minimum recipe): issue next K-step's
// global_load_lds BEFORE computing the current one, single barrier per step.
// With K=512 (only 8 steps) the old stage->drain->compute structure exposed
// the full L2/L3 staging latency every step; this hides it under the MFMAs.
// LDS XOR-swizzle unchanged: 16B chunk c stored at c ^ (row&7) — conflict-free
// b128 reads, staging stays lane-linear for global_load_lds (linear dest +
// inverse-swizzled global source + swizzled read).
__global__ __launch_bounds__(256) void gemm_fused(const ushort_t* __restrict__ Abig,
                                                  const ushort_t* __restrict__ Bbf,
                                                  float* __restrict__ c_pred,
                                                  const float* __restrict__ w,
                                                  float* __restrict__ y) {
    __shared__ __align__(16) ushort_t Atile[2][128 * 64];
    __shared__ __align__(16) ushort_t Btile[2][128 * 64];

    const int tid  = threadIdx.x;
    const int wv   = tid >> 6;
    const int lane = tid & 63;
    const int quad = lane >> 4;
    const int l16  = lane & 15;
    const int bn   = blockIdx.x;   // col tile (fast-varying: A tile reuse in L2)
    const int bm   = blockIdx.y;   // row tile

    const int mi = (wv & 1) * 64;
    const int ni = (wv >> 1) * 64;

    floatx4 acc[4][4] = {};

    const int srow = lane >> 3;       // 0..7 within 8-row staging chunk
    const int schk = lane & 7;        // physical 16B chunk within row

    const ushort_t* gA = Abig + (size_t)(bm * 128) * 512;
    const ushort_t* gB = Bbf  + (size_t)(bn * 128) * 512;

    // LDS dest is wave-uniform base + lane*16B (hardware rule); the swizzle is
    // applied to the per-lane GLOBAL source chunk index `cl`.
#define STAGE(buf, kt)                                                       \
    {                                                                        \
        _Pragma("unroll")                                                    \
        for (int c = 0; c < 4; ++c) {                                        \
            int rowbase = wv * 32 + c * 8;                                   \
            int row = rowbase + srow;                                        \
            int cl  = schk ^ (row & 7);                                      \
            GLOAD_LDS16(gA + (size_t)row * 512 + (kt) * 64 + cl * 8,         \
                        &Atile[buf][rowbase * 64]);                          \
            GLOAD_LDS16(gB + (size_t)row * 512 + (kt) * 64 + cl * 8,         \
                        &Btile[buf][rowbase * 64]);                          \
        }                                                                    \
    }

    STAGE(0, 0);
    __syncthreads();                  // vmcnt drained by syncthreads semantics

    int cur = 0;
    #pragma unroll
    for (int kt = 0; kt < 8; ++kt) {
        // prefetch next K-step into the other buffer (16 loads in flight
        // across the ds_read+MFMA work below)
        if (kt < 7) STAGE(cur ^ 1, kt + 1);

        #pragma unroll
        for (int kk = 0; kk < 2; ++kk) {
            short8 af[4], bf[4];
            #pragma unroll
            for (int fi = 0; fi < 4; ++fi) {
                int row = mi + fi * 16 + l16;
                int cp  = (kk * 4 + quad) ^ (row & 7);
                af[fi] = *(const short8*)(&Atile[cur][row * 64 + cp * 8]);
            }
            #pragma unroll
            for (int fj = 0; fj < 4; ++fj) {
                int row = ni + fj * 16 + l16;
                int cp  = (kk * 4 + quad) ^ (row & 7);
                bf[fj] = *(const short8*)(&Btile[cur][row * 64 + cp * 8]);
            }
            #pragma unroll
            for (int fi = 0; fi < 4; ++fi)
                #pragma unroll
                for (int fj = 0; fj < 4; ++fj)
                    acc[fi][fj] = __builtin_amdgcn_mfma_f32_16x16x32_bf16(
                        af[fi], bf[fj], acc[fi][fj], 0, 0, 0);
        }

        if (kt < 7) {
            __syncthreads();          // drains vmcnt (prefetch landed) + lgkmcnt
            cur ^= 1;
        }
    }
#undef STAGE

    if (bm < 128) {
        // movement rows: write c_pred
        #pragma unroll
        for (int fi = 0; fi < 4; ++fi) {
            #pragma unroll
            for (int reg = 0; reg < 4; ++reg) {
                size_t row = (size_t)bm * 128 + mi + fi * 16 + quad * 4 + reg;
                float* cp = c_pred + row * N_TIMES + bn * 128 + ni + l16;
                #pragma unroll
                for (int fj = 0; fj < 4; ++fj)
                    cp[fj * 16] = acc[fi][fj][reg];
            }
        }
    } else {
        // node rows: y[col] += sum_rows w[n] * f^4   (node id == row index)
        int nb = (bm - 128) * 128;
        float psum[4] = {0.f, 0.f, 0.f, 0.f};
        #pragma unroll
        for (int fj = 0; fj < 4; ++fj)
            #pragma unroll
            for (int fi = 0; fi < 4; ++fi)
                #pragma unroll
                for (int reg = 0; reg < 4; ++reg) {
                    int n = nb + mi + fi * 16 + quad * 4 + reg;
                    float f = acc[fi][fj][reg];
                    float f2 = f * f;
                    psum[fj] += w[n] * f2 * f2;
                }
        #pragma unroll
        for (int fj = 0; fj < 4; ++fj) {
            float v = psum[fj];
            v += __shfl_xor(v, 16);
            v += __shfl_xor(v, 32);
            if (quad == 0)
                atomicAdd(&y[bn * 128 + ni + fj * 16 + l16], v);
        }
    }
}

extern "C" void kernel_launch(void* const* d_in, const int* in_sizes, int n_in,
                              void* d_out, int out_size, void* d_ws, size_t ws_size,
                              hipStream_t stream) {
    const float* x_raw         = (const float*)d_in[0];
    const float* A             = (const float*)d_in[1];
    const float* t_free        = (const float*)d_in[2];
    const float* cap           = (const float*)d_in[3];
    const float* radio         = (const float*)d_in[4];
    const int*   movement_node = (const int*)d_in[5];
    const int*   cdf_node      = (const int*)d_in[6];

    float* out    = (float*)d_out;
    float* x_out  = out;                                  // 512*4096
    float* c_pred = out + (size_t)N_ROUTES * N_TIMES;     // 16384*4096
    float* y      = c_pred + (size_t)N_MOVES * N_TIMES;   // 4096

    char* ws = (char*)d_ws;
    ushort_t* Abig  = (ushort_t*)(ws);                    // 18432*512 bf16
    ushort_t* SAb   = Abig + (size_t)N_MOVES * 512;       // rows 16384..18431
    ushort_t* xTbf  = (ushort_t*)(ws + 18874368);         // 4096*512 bf16
    int*      ncnt  = (int*)(ws + 23068672);
    int*      nlist = (int*)(ws + 23076864);
    float*    w     = (float*)(ws + 23339008);
    float*    basep = (float*)(ws + 23347200);

    hipMemsetAsync(ncnt, 0, N_NODES * sizeof(int), stream);
    hipMemsetAsync(w, 0, N_NODES * sizeof(float), stream);
    hipMemsetAsync(basep, 0, sizeof(float), stream);

    transpose_bf<<<dim3(N_TIMES / 64, N_ROUTES / 64), dim3(256), 0, stream>>>(
        x_raw, x_out, xTbf);

    convA<<<dim3((int)((size_t)N_MOVES * 512 / 8 / 256)), dim3(256), 0, stream>>>(A, Abig);

    build_nodes<<<dim3(N_MOVES / 256), dim3(256), 0, stream>>>(movement_node, ncnt, nlist);

    sa_kernel<<<dim3(N_NODES), dim3(128), 0, stream>>>(A, ncnt, nlist, SAb);

    wsum_kernel<<<dim3(N_CDF / 256), dim3(256), 0, stream>>>(
        t_free, cap, radio, cdf_node, w, basep);

    y_init<<<dim3(N_TIMES / 256), dim3(256), 0, stream>>>(basep, y);

    gemm_fused<<<dim3(N_TIMES / 128, (N_MOVES + N_NODES) / 128), dim3(256), 0, stream>>>(
        Abig, xTbf, c_pred, w, y);
}

// Round 2
// 405.449 us; speedup vs baseline: 1.0185x; 1.0185x over previous
//
#include <hip/hip_runtime.h>

#define N_ROUTES 512
#define N_TIMES  4096
#define N_MOVES  16384
#define N_NODES  2048
#define N_CDF    8192
#define ALPHA    0.15f
#define NODE_CAP 32    // Binomial(16384,1/2048): mean 8 -> P(>32) negligible

typedef unsigned short ushort_t;
typedef __attribute__((ext_vector_type(8))) short short8;
typedef __attribute__((ext_vector_type(4))) float floatx4;

// ---------------- workspace layout (bytes) ----------------
// Abig  : bf16 [18432*512]   off 0           18,874,368   (rows 0..16383 = A, 16384..18431 = SA)
// xTbf  : bf16 [4096*512]    off 18,874,368   4,194,304
// ncnt  : int  [2048]        off 23,068,672       8,192
// nlist : int  [2048*32]     off 23,076,864     262,144
// w     : f32  [2048]        off 23,339,008       8,192
// basep : f32  [1]           off 23,347,200         256
// total ~23.4 MB
// NOTE: gemm tail iterations issue prefetches at k-step 8/9 which read up to
// ~1.3 KB past Abig/xTbf row ends — lands in the adjacent ws regions above
// (mapped memory), staged into LDS buffers that are never read again. Safe.

__device__ inline ushort_t f2bf(float f) {
    union { float f; unsigned u; } v; v.f = f;
    unsigned r = (v.u + 0x7FFFu + ((v.u >> 16) & 1u)) >> 16;
    return (ushort_t)r;
}

// xT[t][k] = bf16(relu(x_raw[k][t])) — LDS tile transpose, both sides coalesced.
// Fused: also writes x_out = relu(x_raw) fp32 (output 0).
__global__ __launch_bounds__(256) void transpose_bf(const float* __restrict__ xr,
                                                    float* __restrict__ xo,
                                                    ushort_t* __restrict__ xT) {
    __shared__ float ld[64][65];
    int t0 = blockIdx.x * 64;
    int k0 = blockIdx.y * 64;
    int tid = threadIdx.x;
    int col = tid & 63;
    #pragma unroll
    for (int i = 0; i < 16; ++i) {
        int row = i * 4 + (tid >> 6);
        float v = fmaxf(xr[(size_t)(k0 + row) * N_TIMES + t0 + col], 0.f);
        ld[row][col] = v;
        xo[(size_t)(k0 + row) * N_TIMES + t0 + col] = v;   // coalesced relu write
    }
    __syncthreads();
    int trow = tid >> 2;
    int kgrp = (tid & 3) * 16;
    ushort_t __align__(16) tmp[16];
    #pragma unroll
    for (int j = 0; j < 16; ++j) tmp[j] = f2bf(ld[kgrp + j][trow]);
    ushort_t* dst = xT + (size_t)(t0 + trow) * 512 + k0 + kgrp;
    *(uint4*)dst       = ((uint4*)tmp)[0];
    *(uint4*)(dst + 8) = ((uint4*)tmp)[1];
}

// A fp32 -> bf16 (0/1 values: exact)
__global__ __launch_bounds__(256) void convA(const float* __restrict__ A,
                                             ushort_t* __restrict__ Ab) {
    size_t i = (size_t)(blockIdx.x * 256 + threadIdx.x) * 8;
    const float4* s = (const float4*)(A + i);
    float4 a = s[0], b = s[1];
    ushort_t __align__(16) t[8] = {f2bf(a.x), f2bf(a.y), f2bf(a.z), f2bf(a.w),
                                   f2bf(b.x), f2bf(b.y), f2bf(b.z), f2bf(b.w)};
    *(uint4*)(Ab + i) = *(uint4*)t;
}

__global__ __launch_bounds__(256) void build_nodes(const int* __restrict__ mnode,
                                                   int* __restrict__ ncnt,
                                                   int* __restrict__ nlist) {
    int m = blockIdx.x * blockDim.x + threadIdx.x;
    if (m >= N_MOVES) return;
    int n = mnode[m];
    int slot = atomicAdd(&ncnt[n], 1);
    if (slot < NODE_CAP) nlist[(size_t)n * NODE_CAP + slot] = m;
}

// SA[n][k] = sum over movements of node n of A[m][k] (small ints, exact in bf16)
__global__ __launch_bounds__(128) void sa_kernel(const float* __restrict__ A,
                                                 const int* __restrict__ ncnt,
                                                 const int* __restrict__ nlist,
                                                 ushort_t* __restrict__ SAb) {
    int n = blockIdx.x, tid = threadIdx.x;
    int cnt = min(ncnt[n], NODE_CAP);
    float acc0 = 0.f, acc1 = 0.f, acc2 = 0.f, acc3 = 0.f;
    for (int j = 0; j < cnt; ++j) {
        int m = nlist[(size_t)n * NODE_CAP + j];
        float4 v = *(const float4*)(A + (size_t)m * 512 + tid * 4);
        acc0 += v.x; acc1 += v.y; acc2 += v.z; acc3 += v.w;
    }
    ushort_t __align__(8) t[4] = {f2bf(acc0), f2bf(acc1), f2bf(acc2), f2bf(acc3)};
    *(uint2*)(SAb + (size_t)n * 512 + tid * 4) = *(uint2*)t;
}

// w[n] = sum_c alpha*t_free*radio/cap^4 ; base = sum_c t_free*radio
__global__ __launch_bounds__(256) void wsum_kernel(const float* __restrict__ t_free,
                                                   const float* __restrict__ cap,
                                                   const float* __restrict__ radio,
                                                   const int* __restrict__ cdf_node,
                                                   float* __restrict__ w,
                                                   float* __restrict__ basep) {
    int c = blockIdx.x * 256 + threadIdx.x;
    float tr = t_free[c] * radio[c];
    float ic = 1.0f / cap[c];
    float ic2 = ic * ic;
    atomicAdd(&w[cdf_node[c]], ALPHA * tr * ic2 * ic2);
    float b = tr;
    #pragma unroll
    for (int d = 32; d >= 1; d >>= 1) b += __shfl_down(b, d);
    if ((threadIdx.x & 63) == 0) atomicAdd(basep, b);
}

__global__ __launch_bounds__(256) void y_init(const float* __restrict__ basep,
                                              float* __restrict__ y) {
    y[blockIdx.x * 256 + threadIdx.x] = *basep;
}

#define GLOAD_LDS16(g, l) __builtin_amdgcn_global_load_lds( \
    (const __attribute__((address_space(1))) void*)(g),     \
    (__attribute__((address_space(3))) void*)(l), 16, 0, 0)

// ============================================================================
// Fused GEMM v3: 256x256 tile, BK=64, 512 thr (8 waves: 2M x 4N, 128x64 each),
// 8-phase schedule (T3+T4), counted vmcnt (never 0 in loop), setprio (T5),
// XOR-swizzled LDS (T2), bijective XCD block swizzle (T1).
//
// LDS 128 KiB: AE/AO/BE/BO = 4 x [256 rows][64 k] bf16 (32 KiB each).
// Iteration t computes K-steps e=2t (E bufs) and o=2t+1 (O bufs) in 8 phases:
//   ph0: read A(qm0),B(qn0) from E | stage O.A-h0(step o)  | bar | mfma q00 | bar
//   ph1: read B(qn1) from E        | stage O.A-h1(step o)  | bar | mfma q01 | bar
//   ph2: read A(qm1) from E        | stage E.B-h0(step e+2)| bar | mfma q10 | bar
//   ph3:                           | stage E.B-h1(step e+2)| vmcnt(4) bar | mfma q11 | bar
//   ph4..7: same pattern on O bufs; stages: E.A-h0, E.A-h1 (e+2), O.B-h0, O.B-h1 (o+2)
//   end of ph7: vmcnt(4) before the closing barrier.
// vmcnt(4) = 2 newest half-tile stages (2 loads each) may remain in flight;
// everything a subsequent phase reads is provably landed (in-order vmcnt).
// Write-after-read: every stage targets a region whose last reader was in an
// earlier phase (barrier-separated). Tail (t=3) stages k-steps 8/9 = garbage
// into buffers never read again (keeps counts uniform, no branches).
// ============================================================================
__global__ __launch_bounds__(512, 2) void gemm_fused(const ushort_t* __restrict__ Abig,
                                                     const ushort_t* __restrict__ Bbf,
                                                     float* __restrict__ c_pred,
                                                     const float* __restrict__ w,
                                                     float* __restrict__ y) {
    __shared__ __align__(16) ushort_t lds[4][256 * 64];   // AE, AO, BE, BO

    const int tid  = threadIdx.x;
    const int wv   = tid >> 6;          // 0..7
    const int lane = tid & 63;
    const int quad = lane >> 4;
    const int l16  = lane & 15;
    const int wr   = wv >> 2;           // 0..1  M-split
    const int wc   = wv & 3;            // 0..3  N-split

    // XCD-aware bijective swizzle: 1152 blocks = 8 XCDs x 144.  Each XCD gets
    // 9 consecutive bm row-panels (A panels L2-resident), bn fastest within.
    const int bid = blockIdx.x;
    const int swz = (bid & 7) * 144 + (bid >> 3);
    const int bm  = swz >> 4;           // 0..71
    const int bn  = swz & 15;           // 0..15

    ushort_t* AE = &lds[0][0];
    ushort_t* AO = &lds[1][0];
    ushort_t* BE = &lds[2][0];
    ushort_t* BO = &lds[3][0];

    const ushort_t* gA = Abig + (size_t)bm * 256 * 512;
    const ushort_t* gB = Bbf  + (size_t)bn * 256 * 512;

    const int rr = wv * 8 + (lane >> 3);          // staging row within 64-row group
    const int cl = (lane & 7) ^ (lane >> 3);      // pre-swizzled global chunk

    // Stage rows [r0, r0+128) of one operand tile at k-step kt (2 loads/thread).
    // LDS dest lane-linear (HW: wave-uniform base + lane*16B); source chunk
    // pre-swizzled so LDS[row][c] holds global chunk c ^ (row&7).
#define STAGE_HALF(T, G, r0, kt) do {                                          \
        GLOAD_LDS16((G) + (size_t)((r0) + rr) * 512 + (kt) * 64 + cl * 8,      \
                    (T) + ((r0) + wv * 8) * 64);                               \
        GLOAD_LDS16((G) + (size_t)((r0) + 64 + rr) * 512 + (kt) * 64 + cl * 8, \
                    (T) + ((r0) + 64 + wv * 8) * 64);                          \
    } while (0)

#define BAR()  asm volatile("s_barrier" ::: "memory")
#define VMC4() asm volatile("s_waitcnt vmcnt(4)" ::: "memory")

    short8 af[4][2];        // A-frags of current qm quadrant (fi x kk)
    short8 b0[2][2];        // B-frags qn=0 (fjl x kk)
    short8 b1[2][2];        // B-frags qn=1
    floatx4 acc[8][4] = {}; // 128 VGPRs

#define READ_A(T, qm) do {                                                     \
        _Pragma("unroll")                                                      \
        for (int fi = 0; fi < 4; ++fi) {                                       \
            int row = wr * 128 + (qm) * 64 + fi * 16 + l16;                    \
            const ushort_t* p = (T) + row * 64;                                \
            af[fi][0] = *(const short8*)(p + ((quad       ^ (l16 & 7)) * 8));  \
            af[fi][1] = *(const short8*)(p + (((4 + quad) ^ (l16 & 7)) * 8));  \
        }                                                                      \
    } while (0)

#define READ_B(T, qn, B) do {                                                  \
        _Pragma("unroll")                                                      \
        for (int fj = 0; fj < 2; ++fj) {                                       \
            int row = wc * 64 + (qn) * 32 + fj * 16 + l16;                     \
            const ushort_t* p = (T) + row * 64;                                \
            B[fj][0] = *(const short8*)(p + ((quad       ^ (l16 & 7)) * 8));   \
            B[fj][1] = *(const short8*)(p + (((4 + quad) ^ (l16 & 7)) * 8));   \
        }                                                                      \
    } while (0)

#define MFMA_Q(qm, qn, B) do {                                                 \
        __builtin_amdgcn_s_setprio(1);                                         \
        _Pragma("unroll")                                                      \
        for (int kk = 0; kk < 2; ++kk)                                         \
            _Pragma("unroll")                                                  \
            for (int fi = 0; fi < 4; ++fi)                                     \
                _Pragma("unroll")                                              \
                for (int fj = 0; fj < 2; ++fj)                                 \
                    acc[(qm) * 4 + fi][(qn) * 2 + fj] =                        \
                        __builtin_amdgcn_mfma_f32_16x16x32_bf16(               \
                            af[fi][kk], B[fj][kk],                             \
                            acc[(qm) * 4 + fi][(qn) * 2 + fj], 0, 0, 0);       \
        __builtin_amdgcn_s_setprio(0);                                         \
    } while (0)

    // ---- prologue: stage step0 (E.A, E.B) + step1's B (O.B) ----
    STAGE_HALF(AE, gA, 0, 0);   STAGE_HALF(AE, gA, 128, 0);
    STAGE_HALF(BE, gB, 0, 0);   STAGE_HALF(BE, gB, 128, 0);
    STAGE_HALF(BO, gB, 0, 1);   STAGE_HALF(BO, gB, 128, 1);
    VMC4();                     // E fully landed; O.B (newest 4 loads) in flight
    BAR();

    for (int t = 0; t < 4; ++t) {
        const int o  = 2 * t + 1;
        const int e2 = 2 * t + 2;   // t=3: 8/9 = safe garbage prefetch
        const int o2 = 2 * t + 3;

        // ph0
        READ_A(AE, 0); READ_B(BE, 0, b0);
        STAGE_HALF(AO, gA, 0, o);
        BAR(); MFMA_Q(0, 0, b0); BAR();
        // ph1
        READ_B(BE, 1, b1);
        STAGE_HALF(AO, gA, 128, o);
        BAR(); MFMA_Q(0, 1, b1); BAR();
        // ph2
        READ_A(AE, 1);
        STAGE_HALF(BE, gB, 0, e2);
        BAR(); MFMA_Q(1, 0, b0); BAR();
        // ph3  (checkpoint: O.A + O.B landed before ph4 reads them)
        STAGE_HALF(BE, gB, 128, e2);
        VMC4();
        BAR(); MFMA_Q(1, 1, b1); BAR();
        // ph4
        READ_A(AO, 0); READ_B(BO, 0, b0);
        STAGE_HALF(AE, gA, 0, e2);
        BAR(); MFMA_Q(0, 0, b0); BAR();
        // ph5
        READ_B(BO, 1, b1);
        STAGE_HALF(AE, gA, 128, e2);
        BAR(); MFMA_Q(0, 1, b1); BAR();
        // ph6
        READ_A(AO, 1);
        STAGE_HALF(BO, gB, 0, o2);
        BAR(); MFMA_Q(1, 0, b0); BAR();
        // ph7  (checkpoint: E.A + E.B landed before next-iter ph0 reads)
        STAGE_HALF(BO, gB, 128, o2);
        VMC4();
        BAR(); MFMA_Q(1, 1, b1); BAR();
    }

#undef STAGE_HALF
#undef READ_A
#undef READ_B
#undef MFMA_Q
#undef BAR
#undef VMC4

    if (bm < 64) {
        // movement rows: write c_pred
        #pragma unroll
        for (int fi = 0; fi < 8; ++fi) {
            #pragma unroll
            for (int reg = 0; reg < 4; ++reg) {
                size_t row = (size_t)bm * 256 + wr * 128 + fi * 16 + quad * 4 + reg;
                float* cp = c_pred + row * N_TIMES + bn * 256 + wc * 64 + l16;
                #pragma unroll
                for (int fj = 0; fj < 4; ++fj)
                    cp[fj * 16] = acc[fi][fj][reg];
            }
        }
    } else {
        // node rows: y[col] += sum_rows w[n] * f^4   (node id == row index)
        int nb = (bm - 64) * 256 + wr * 128;
        float psum[4] = {0.f, 0.f, 0.f, 0.f};
        #pragma unroll
        for (int fj = 0; fj < 4; ++fj)
            #pragma unroll
            for (int fi = 0; fi < 8; ++fi)
                #pragma unroll
                for (int reg = 0; reg < 4; ++reg) {
                    int n = nb + fi * 16 + quad * 4 + reg;
                    float f = acc[fi][fj][reg];
                    float f2 = f * f;
                    psum[fj] += w[n] * f2 * f2;
                }
        #pragma unroll
        for (int fj = 0; fj < 4; ++fj) {
            float v = psum[fj];
            v += __shfl_xor(v, 16);
            v += __shfl_xor(v, 32);
            if (quad == 0)
                atomicAdd(&y[bn * 256 + wc * 64 + fj * 16 + l16], v);
        }
    }
}

extern "C" void kernel_launch(void* const* d_in, const int* in_sizes, int n_in,
                              void* d_out, int out_size, void* d_ws, size_t ws_size,
                              hipStream_t stream) {
    const float* x_raw         = (const float*)d_in[0];
    const float* A             = (const float*)d_in[1];
    const float* t_free        = (const float*)d_in[2];
    const float* cap           = (const float*)d_in[3];
    const float* radio         = (const float*)d_in[4];
    const int*   movement_node = (const int*)d_in[5];
    const int*   cdf_node      = (const int*)d_in[6];

    float* out    = (float*)d_out;
    float* x_out  = out;                                  // 512*4096
    float* c_pred = out + (size_t)N_ROUTES * N_TIMES;     // 16384*4096
    float* y      = c_pred + (size_t)N_MOVES * N_TIMES;   // 4096

    char* ws = (char*)d_ws;
    ushort_t* Abig  = (ushort_t*)(ws);                    // 18432*512 bf16
    ushort_t* SAb   = Abig + (size_t)N_MOVES * 512;       // rows 16384..18431
    ushort_t* xTbf  = (ushort_t*)(ws + 18874368);         // 4096*512 bf16
    int*      ncnt  = (int*)(ws + 23068672);
    int*      nlist = (int*)(ws + 23076864);
    float*    w     = (float*)(ws + 23339008);
    float*    basep = (float*)(ws + 23347200);

    hipMemsetAsync(ncnt, 0, N_NODES * sizeof(int), stream);
    hipMemsetAsync(w, 0, N_NODES * sizeof(float), stream);
    hipMemsetAsync(basep, 0, sizeof(float), stream);

    transpose_bf<<<dim3(N_TIMES / 64, N_ROUTES / 64), dim3(256), 0, stream>>>(
        x_raw, x_out, xTbf);

    convA<<<dim3((int)((size_t)N_MOVES * 512 / 8 / 256)), dim3(256), 0, stream>>>(A, Abig);

    build_nodes<<<dim3(N_MOVES / 256), dim3(256), 0, stream>>>(movement_node, ncnt, nlist);

    sa_kernel<<<dim3(N_NODES), dim3(128), 0, stream>>>(A, ncnt, nlist, SAb);

    wsum_kernel<<<dim3(N_CDF / 256), dim3(256), 0, stream>>>(
        t_free, cap, radio, cdf_node, w, basep);

    y_init<<<dim3(N_TIMES / 256), dim3(256), 0, stream>>>(basep, y);

    gemm_fused<<<dim3((N_TIMES / 256) * ((N_MOVES + N_NODES) / 256)), dim3(512), 0, stream>>>(
        Abig, xTbf, c_pred, w, y);
}